// Round 2
// baseline (3708.998 us; speedup 1.0000x reference)
//
#include <hip/hip_runtime.h>
#include <hip/hip_bf16.h>
#include <stdint.h>

// Problem constants (fixed by setup_inputs)
#define BB 8
#define NN 16384
#define GG 1024
#define SS 32
#define BN (BB*NN)          // 131072

// Output offsets (elements, float32)
#define OFF_SIDX 0
#define OFF_SN   8192
#define OFF_SXYZ 770048     // 8192 + 8192*31*3
#define OFF_ORD  794624     // + 24576
#define OFF_INV  827392     // + 32768

// Workspace offsets (bytes)
#define WS_SIDX 0                    // int[8192]
#define WS_KNN  32768                // int[8192*32] = 1 MB

static __device__ __forceinline__ uint64_t shfl_u64(uint64_t v, int src) {
    int lo = __shfl((int)(uint32_t)(v & 0xffffffffull), src, 64);
    int hi = __shfl((int)(uint32_t)(v >> 32), src, 64);
    return ((uint64_t)(uint32_t)hi << 32) | (uint32_t)lo;
}

// ---------------------------------------------------------------------------
// 1) Farthest point sampling: one block per batch, 1024 threads, 16 pts/thread
// ---------------------------------------------------------------------------
__global__ __launch_bounds__(1024) void fps_kernel(const float* __restrict__ coord,
                                                   int* __restrict__ ws_sidx,
                                                   float* __restrict__ out) {
#pragma clang fp contract(off)
    const int b = blockIdx.x;
    const int t = threadIdx.x;
    const int base = b * NN;

    float px[16], py[16], pz[16], dist[16];
#pragma unroll
    for (int j = 0; j < 16; j++) {
        int p = t + (j << 10);
        px[j] = coord[3*(base+p)];
        py[j] = coord[3*(base+p)+1];
        pz[j] = coord[3*(base+p)+2];
        dist[j] = __builtin_inff();
    }

    __shared__ float wv[16];
    __shared__ int   wp[16];
    __shared__ float sq[3];

    if (t == 0) {
        ws_sidx[b*GG] = base;                          // selection 0 = index 0
        out[OFF_SIDX + b*GG] = (float)base;
        sq[0] = px[0]; sq[1] = py[0]; sq[2] = pz[0];   // pts[0] (t==0,j==0)
    }
    __syncthreads();
    float qx = sq[0], qy = sq[1], qz = sq[2];
    const int wave = t >> 6, lane = t & 63;

    for (int g = 1; g < GG; g++) {
        // local scan: update min-dist, track argmax (first-max: strict >)
        float bv = -1.0f; int bj = 0;
#pragma unroll
        for (int j = 0; j < 16; j++) {
            float dx = px[j]-qx, dy = py[j]-qy, dz = pz[j]-qz;
            float d  = (dx*dx + dy*dy) + dz*dz;        // match np: no fma, left-assoc
            float nd = fminf(dist[j], d);
            dist[j] = nd;
            if (nd > bv) { bv = nd; bj = j; }
        }
        int bp = t + (bj << 10);
        // wave butterfly argmax, tie -> smaller index
#pragma unroll
        for (int off = 32; off >= 1; off >>= 1) {
            float ov = __shfl_xor(bv, off, 64);
            int   op = __shfl_xor(bp, off, 64);
            if (ov > bv || (ov == bv && op < bp)) { bv = ov; bp = op; }
        }
        if (lane == 0) { wv[wave] = bv; wp[wave] = bp; }
        __syncthreads();
        // every thread reduces the 16 wave winners (width-16 butterfly)
        float rv = wv[lane & 15]; int rp = wp[lane & 15];
#pragma unroll
        for (int off = 8; off >= 1; off >>= 1) {
            float ov = __shfl_xor(rv, off, 16);
            int   op = __shfl_xor(rp, off, 16);
            if (ov > rv || (ov == rv && op < rp)) { rv = ov; rp = op; }
        }
        // owner thread publishes winner coords (select chain, no global reload)
        if (t == (rp & 1023)) {
            int jj = rp >> 10;
            float ax = px[0], ay = py[0], az = pz[0];
#pragma unroll
            for (int j = 1; j < 16; j++) {
                bool c = (jj == j);
                ax = c ? px[j] : ax; ay = c ? py[j] : ay; az = c ? pz[j] : az;
            }
            sq[0] = ax; sq[1] = ay; sq[2] = az;
        }
        if (t == 0) {
            ws_sidx[b*GG + g] = base + rp;
            out[OFF_SIDX + b*GG + g] = (float)(base + rp);
        }
        __syncthreads();
        qx = sq[0]; qy = sq[1]; qz = sq[2];
    }
}

// ---------------------------------------------------------------------------
// 2) kNN top-32 per center: one wave per center, d2 staged in 64KB LDS,
//    32x (butterfly argmin + winner-stripe rescan), consumed masks in regs.
// ---------------------------------------------------------------------------
__global__ __launch_bounds__(64) void knn_kernel(const float* __restrict__ coord,
                                                 const int* __restrict__ ws_sidx,
                                                 int* __restrict__ ws_knn) {
#pragma clang fp contract(off)
    __shared__ float d2s[16384];          // exactly 64 KB
    const int c = blockIdx.x;             // center 0..8191
    const int l = threadIdx.x;            // lane 0..63
    const int b = c >> 10;
    const int base = b * NN;
    const int sg = ws_sidx[c];            // global center index
    const float cx = coord[3*sg], cy = coord[3*sg+1], cz = coord[3*sg+2];
    const float cc = (cx*cx + cy*cy) + cz*cz;

    // phase 1: d2 for stripe {l + 64*j}, swizzled LDS slot (conflict-free)
    float mv = __builtin_inff(); int mp = 0;
#pragma unroll 4
    for (int j = 0; j < 256; j++) {
        int p = l + (j << 6);
        float x = coord[3*(base+p)], y = coord[3*(base+p)+1], z = coord[3*(base+p)+2];
        float pp  = (x*x + y*y) + z*z;
        float dot = (cx*x + cy*y) + cz*z;
        float d2  = (cc + pp) - 2.0f*dot;             // match ref formula exactly
        d2s[(l << 8) + ((j + l) & 255)] = d2;
        if (d2 < mv) { mv = d2; mp = p; }             // j asc => p asc, strict <
    }
    __syncthreads();  // single-wave barrier: drain LDS writes before cross-lane reads

    uint64_t m0 = 0, m1 = 0, m2 = 0, m3 = 0;          // consumed bits, my stripe
    int res_p = 0;
    for (int k = 0; k < SS; k++) {
        // global argmin over per-lane minima (tie -> smaller index)
        float bv = mv; int bp = mp;
#pragma unroll
        for (int off = 32; off >= 1; off >>= 1) {
            float ov = __shfl_xor(bv, off, 64);
            int   op = __shfl_xor(bp, off, 64);
            if (ov < bv || (ov == bv && op < bp)) { bv = ov; bp = op; }
        }
        if (l == k) res_p = bp;                       // lane k keeps k-th neighbor
        const int w  = bp & 63;                       // winner lane / stripe
        const int e  = bp >> 6;                       // element within stripe
        if (l == w) {                                 // mark consumed
            uint64_t bit = 1ull << (e & 63);
            int word = e >> 6;
            if      (word == 0) m0 |= bit;
            else if (word == 1) m1 |= bit;
            else if (word == 2) m2 |= bit;
            else                m3 |= bit;
        }
        uint64_t w0 = shfl_u64(m0, w), w1 = shfl_u64(m1, w),
                 w2 = shfl_u64(m2, w), w3 = shfl_u64(m3, w);
        // rescan winner stripe (256 elems, 4/lane; bit index == lane)
        float nv = __builtin_inff(); int np_ = 0;
#pragma unroll
        for (int m = 0; m < 4; m++) {
            int e2 = l + (m << 6);
            uint64_t mw = (m == 0) ? w0 : ((m == 1) ? w1 : ((m == 2) ? w2 : w3));
            float v = d2s[(w << 8) + ((e2 + w) & 255)];
            bool cons = (mw >> l) & 1ull;
            int p2 = w + (e2 << 6);
            if (!cons && v < nv) { nv = v; np_ = p2; } // m asc => p2 asc
        }
#pragma unroll
        for (int off = 32; off >= 1; off >>= 1) {
            float ov = __shfl_xor(nv, off, 64);
            int   op = __shfl_xor(np_, off, 64);
            if (ov < nv || (ov == nv && op < np_)) { nv = ov; np_ = op; }
        }
        if (l == w) { mv = nv; mp = np_; }            // winner lane's new stripe-min
    }
    if (l < SS) ws_knn[c * SS + l] = res_p;           // local point index
}

// ---------------------------------------------------------------------------
// 3) s_xyz gather
// ---------------------------------------------------------------------------
__global__ void sxyz_kernel(const float* __restrict__ coord,
                            const int* __restrict__ ws_sidx,
                            float* __restrict__ out) {
    int t = blockIdx.x * blockDim.x + threadIdx.x;
    if (t < 8192*3) {
        int i = t / 3, cmp = t - 3*i;
        out[OFF_SXYZ + t] = coord[3*ws_sidx[i] + cmp];
    }
}

// ---------------------------------------------------------------------------
// 4) s_n = coord[knn[1..31]] - center
// ---------------------------------------------------------------------------
__global__ void sn_kernel(const float* __restrict__ coord,
                          const int* __restrict__ ws_sidx,
                          const int* __restrict__ ws_knn,
                          float* __restrict__ out) {
#pragma clang fp contract(off)
    int t = blockIdx.x * blockDim.x + threadIdx.x;
    if (t < 8192*31*3) {
        int cmp = t % 3; int rem = t / 3;
        int j = rem % 31; int i = rem / 31;
        int b = i >> 10;
        int nb = ws_knn[i*SS + j + 1];                // skip neighbor 0 (self)
        int gidx = b*NN + nb;
        float v = coord[3*gidx + cmp] - coord[3*ws_sidx[i] + cmp];
        out[OFF_SN + t] = v;
    }
}

// ---------------------------------------------------------------------------
// 5) stable argsort per code row: bitonic sort of (code<<13 | idx) in LDS
// ---------------------------------------------------------------------------
__global__ __launch_bounds__(1024) void sort_kernel(const int* __restrict__ ser,
                                                    const int* __restrict__ ws_sidx,
                                                    float* __restrict__ out) {
    __shared__ uint64_t keys[8192];                   // 64 KB
    const int r = blockIdx.x, t = threadIdx.x;
#pragma unroll
    for (int s = 0; s < 8; s++) {
        int i = t + (s << 10);
        uint32_t code = (uint32_t)ser[r * BN + ws_sidx[i]];   // < 2^30
        keys[i] = ((uint64_t)code << 13) | (uint32_t)i;       // unique keys => stable
    }
    __syncthreads();
    for (int k2 = 2; k2 <= 8192; k2 <<= 1) {
        for (int j = k2 >> 1; j > 0; j >>= 1) {
#pragma unroll 2
            for (int s = 0; s < 8; s++) {
                int i = t + (s << 10);
                int ixj = i ^ j;
                if (ixj > i) {
                    uint64_t a = keys[i], bq = keys[ixj];
                    bool up = ((i & k2) == 0);
                    if ((a > bq) == up) { keys[i] = bq; keys[ixj] = a; }
                }
            }
            __syncthreads();
        }
    }
    for (int s = 0; s < 8; s++) {
        int k = t + (s << 10);
        uint64_t key = keys[k];
        int i = (int)(key & 8191u);
        out[OFF_ORD + r*8192 + k] = (float)i;
        out[OFF_INV + r*8192 + i] = (float)k;
    }
}

// ---------------------------------------------------------------------------
extern "C" void kernel_launch(void* const* d_in, const int* in_sizes, int n_in,
                              void* d_out, int out_size, void* d_ws, size_t ws_size,
                              hipStream_t stream) {
    const float* coord = (const float*)d_in[0];
    const int*   ser   = (const int*)d_in[1];
    float* out = (float*)d_out;
    char* ws = (char*)d_ws;
    int* ws_sidx = (int*)(ws + WS_SIDX);
    int* ws_knn  = (int*)(ws + WS_KNN);

    hipLaunchKernelGGL(fps_kernel,  dim3(BB),   dim3(1024), 0, stream, coord, ws_sidx, out);
    hipLaunchKernelGGL(knn_kernel,  dim3(8192), dim3(64),   0, stream, coord, ws_sidx, ws_knn);
    hipLaunchKernelGGL(sxyz_kernel, dim3(96),   dim3(256),  0, stream, coord, ws_sidx, out);
    hipLaunchKernelGGL(sn_kernel,   dim3(2976), dim3(256),  0, stream, coord, ws_sidx, ws_knn, out);
    hipLaunchKernelGGL(sort_kernel, dim3(4),    dim3(1024), 0, stream, ser, ws_sidx, out);
}

// Round 3
// 2296.732 us; speedup vs baseline: 1.6149x; 1.6149x over previous
//
#include <hip/hip_runtime.h>
#include <hip/hip_bf16.h>
#include <stdint.h>

// Problem constants (fixed by setup_inputs)
#define BB 8
#define NN 16384
#define GG 1024
#define SS 32
#define BN (BB*NN)          // 131072

// Output offsets (elements, float32)
#define OFF_SIDX 0
#define OFF_SN   8192
#define OFF_SXYZ 770048     // 8192 + 8192*31*3
#define OFF_ORD  794624     // + 24576
#define OFF_INV  827392     // + 32768

// Workspace offsets (bytes)
#define WS_SIDX 0                    // int[8192]
#define WS_KNN  32768                // int[8192*32] = 1 MB

typedef float v2f __attribute__((ext_vector_type(2)));

static __device__ __forceinline__ v2f vmin2(v2f a, v2f b) {
    v2f r; r.x = fminf(a.x, b.x); r.y = fminf(a.y, b.y); return r;
}
static __device__ __forceinline__ v2f vmax2(v2f a, v2f b) {
    v2f r; r.x = fmaxf(a.x, b.x); r.y = fmaxf(a.y, b.y); return r;
}

static __device__ __forceinline__ uint64_t shfl_u64(uint64_t v, int src) {
    int lo = __shfl((int)(uint32_t)(v & 0xffffffffull), src, 64);
    int hi = __shfl((int)(uint32_t)(v >> 32), src, 64);
    return ((uint64_t)(uint32_t)hi << 32) | (uint32_t)lo;
}

// ---------------------------------------------------------------------------
// 1) FPS: one block/batch, 1024 thr, 16 pts/thread as 8 float2 pairs.
//    Per step: pk-vectorized dist update -> value-only block argmax ->
//    claimants resolve exact first-max index via LDS atomicMin on packed p.
// ---------------------------------------------------------------------------
__global__ __launch_bounds__(1024) void fps_kernel(const float* __restrict__ coord,
                                                   int* __restrict__ ws_sidx,
                                                   float* __restrict__ out) {
#pragma clang fp contract(off)
    const int b = blockIdx.x;
    const int t = threadIdx.x;
    const int base = b * NN;
    const int wave = t >> 6, lane = t & 63;

    // pair j covers point indices e=2j (x-slot) and e=2j+1 (y-slot), p = t + e*1024
    v2f px[8], py[8], pz[8], dist[8];
#pragma unroll
    for (int j = 0; j < 8; j++) {
        int pA = t + (j << 11);
        int pB = pA + 1024;
        px[j] = (v2f){coord[3*(base+pA)  ], coord[3*(base+pB)  ]};
        py[j] = (v2f){coord[3*(base+pA)+1], coord[3*(base+pB)+1]};
        pz[j] = (v2f){coord[3*(base+pA)+2], coord[3*(base+pB)+2]};
        dist[j] = (v2f){__builtin_inff(), __builtin_inff()};
    }

    __shared__ float wv[16];
    __shared__ unsigned win[2];

    if (t == 0) {
        ws_sidx[b*GG] = base;                 // selection 0 = index 0
        out[OFF_SIDX + b*GG] = (float)base;
        win[0] = 0xffffffffu; win[1] = 0xffffffffu;
    }
    // q0 = pts[0] (broadcast global load; batch is L2-resident)
    float qx = coord[3*base], qy = coord[3*base+1], qz = coord[3*base+2];
    __syncthreads();

    for (int g = 1; g < GG; g++) {
        const int s = g & 1;
        // ---- scan: dist = min(dist, |p-q|^2), bit-exact (no fma, left-assoc)
        v2f qvx = (v2f){qx,qx}, qvy = (v2f){qy,qy}, qvz = (v2f){qz,qz};
#pragma unroll
        for (int j = 0; j < 8; j++) {
            v2f dx = px[j] - qvx, dy = py[j] - qvy, dz = pz[j] - qvz;
            v2f d  = (dx*dx + dy*dy) + dz*dz;
            dist[j] = vmin2(dist[j], d);
        }
        // ---- per-thread max (value only), tree
        v2f m01 = vmax2(dist[0], dist[1]);
        v2f m23 = vmax2(dist[2], dist[3]);
        v2f m45 = vmax2(dist[4], dist[5]);
        v2f m67 = vmax2(dist[6], dist[7]);
        v2f m03 = vmax2(m01, m23);
        v2f m47 = vmax2(m45, m67);
        v2f m07 = vmax2(m03, m47);
        float bv = fmaxf(m07.x, m07.y);
        // ---- wave max (value only)
        float gv = bv;
#pragma unroll
        for (int off = 32; off >= 1; off >>= 1)
            gv = fmaxf(gv, __shfl_xor(gv, off, 64));
        if (lane == 0) wv[wave] = gv;
        __syncthreads();                       // B1: wv ready; win[s] reads of g-1 done
        if (t == 0) win[1 - s] = 0xffffffffu;  // reset other slot for step g+1
        // ---- block max from 16 wave winners
        float rv = wv[lane & 15];
#pragma unroll
        for (int off = 8; off >= 1; off >>= 1)
            rv = fmaxf(rv, __shfl_xor(rv, off, 16));
        // ---- claim: exact first-max index = min p, p = t + e*1024
        if (bv == rv) {
            int e = 15;
#pragma unroll
            for (int jj = 15; jj >= 0; jj--) {
                float v = (jj & 1) ? dist[jj >> 1].y : dist[jj >> 1].x;
                if (v == rv) e = jj;
            }
            atomicMin(&win[s], (unsigned)(t + (e << 10)));
        }
        __syncthreads();                       // B2: winner resolved
        unsigned pw = win[s];
        if (t == 0) {
            ws_sidx[b*GG + g] = base + (int)pw;
            out[OFF_SIDX + b*GG + g] = (float)(base + (int)pw);
        }
        qx = coord[3*(base+(int)pw)];
        qy = coord[3*(base+(int)pw)+1];
        qz = coord[3*(base+(int)pw)+2];
    }
}

// ---------------------------------------------------------------------------
// 2) kNN top-32: one wave per center, NO LDS (d2 recomputed on rescan ->
//    full occupancy: all 8192 waves resident). Bit-exact d2 both passes.
// ---------------------------------------------------------------------------
__global__ __launch_bounds__(64) void knn_kernel(const float* __restrict__ coord,
                                                 const int* __restrict__ ws_sidx,
                                                 int* __restrict__ ws_knn) {
#pragma clang fp contract(off)
    const int c = blockIdx.x;             // center 0..8191
    const int l = threadIdx.x;            // lane 0..63
    const int b = c >> 10;
    const int base = b * NN;
    const int sg = ws_sidx[c];            // global center index
    const float cx = coord[3*sg], cy = coord[3*sg+1], cz = coord[3*sg+2];
    const float cc = (cx*cx + cy*cy) + cz*cz;

    // phase 1: per-lane running min over stripe {l + 64*j}
    float mv = __builtin_inff(); int mp = 0;
#pragma unroll 4
    for (int j = 0; j < 256; j++) {
        int p = l + (j << 6);
        float x = coord[3*(base+p)], y = coord[3*(base+p)+1], z = coord[3*(base+p)+2];
        float pp  = (x*x + y*y) + z*z;
        float dot = (cx*x + cy*y) + cz*z;
        float d2  = (cc + pp) - 2.0f*dot;             // ref formula exactly
        if (d2 < mv) { mv = d2; mp = p; }             // j asc => p asc, strict <
    }

    uint64_t m0 = 0, m1 = 0, m2 = 0, m3 = 0;          // consumed bits, my stripe
    int res_p = 0;
    for (int k = 0; k < SS; k++) {
        // global argmin over per-lane minima (tie -> smaller index)
        float bv = mv; int bp = mp;
#pragma unroll
        for (int off = 32; off >= 1; off >>= 1) {
            float ov = __shfl_xor(bv, off, 64);
            int   op = __shfl_xor(bp, off, 64);
            if (ov < bv || (ov == bv && op < bp)) { bv = ov; bp = op; }
        }
        if (l == k) res_p = bp;                       // lane k keeps k-th neighbor
        const int w  = bp & 63;                       // winner lane / stripe
        const int e  = bp >> 6;                       // element within stripe
        if (l == w) {                                 // mark consumed
            uint64_t bit = 1ull << (e & 63);
            int word = e >> 6;
            if      (word == 0) m0 |= bit;
            else if (word == 1) m1 |= bit;
            else if (word == 2) m2 |= bit;
            else                m3 |= bit;
        }
        uint64_t w0 = shfl_u64(m0, w), w1 = shfl_u64(m1, w),
                 w2 = shfl_u64(m2, w), w3 = shfl_u64(m3, w);
        // rescan winner stripe (256 elems, 4/lane), d2 recomputed (bit-exact)
        float nv = __builtin_inff(); int np_ = 0;
#pragma unroll
        for (int m = 0; m < 4; m++) {
            int e2 = l + (m << 6);
            uint64_t mw = (m == 0) ? w0 : ((m == 1) ? w1 : ((m == 2) ? w2 : w3));
            int p2 = w + (e2 << 6);
            float x = coord[3*(base+p2)], y = coord[3*(base+p2)+1], z = coord[3*(base+p2)+2];
            float pp  = (x*x + y*y) + z*z;
            float dot = (cx*x + cy*y) + cz*z;
            float d2  = (cc + pp) - 2.0f*dot;
            bool cons = (mw >> l) & 1ull;
            if (!cons && d2 < nv) { nv = d2; np_ = p2; } // m asc => p2 asc
        }
#pragma unroll
        for (int off = 32; off >= 1; off >>= 1) {
            float ov = __shfl_xor(nv, off, 64);
            int   op = __shfl_xor(np_, off, 64);
            if (ov < nv || (ov == nv && op < np_)) { nv = ov; np_ = op; }
        }
        if (l == w) { mv = nv; mp = np_; }            // winner lane's new stripe-min
    }
    if (l < SS) ws_knn[c * SS + l] = res_p;           // local point index
}

// ---------------------------------------------------------------------------
// 3) s_xyz gather
// ---------------------------------------------------------------------------
__global__ void sxyz_kernel(const float* __restrict__ coord,
                            const int* __restrict__ ws_sidx,
                            float* __restrict__ out) {
    int t = blockIdx.x * blockDim.x + threadIdx.x;
    if (t < 8192*3) {
        int i = t / 3, cmp = t - 3*i;
        out[OFF_SXYZ + t] = coord[3*ws_sidx[i] + cmp];
    }
}

// ---------------------------------------------------------------------------
// 4) s_n = coord[knn[1..31]] - center
// ---------------------------------------------------------------------------
__global__ void sn_kernel(const float* __restrict__ coord,
                          const int* __restrict__ ws_sidx,
                          const int* __restrict__ ws_knn,
                          float* __restrict__ out) {
#pragma clang fp contract(off)
    int t = blockIdx.x * blockDim.x + threadIdx.x;
    if (t < 8192*31*3) {
        int cmp = t % 3; int rem = t / 3;
        int j = rem % 31; int i = rem / 31;
        int b = i >> 10;
        int nb = ws_knn[i*SS + j + 1];                // skip neighbor 0 (self)
        int gidx = b*NN + nb;
        float v = coord[3*gidx + cmp] - coord[3*ws_sidx[i] + cmp];
        out[OFF_SN + t] = v;
    }
}

// ---------------------------------------------------------------------------
// 5) stable argsort per code row: bitonic sort of (code<<13 | idx) in LDS
// ---------------------------------------------------------------------------
__global__ __launch_bounds__(1024) void sort_kernel(const int* __restrict__ ser,
                                                    const int* __restrict__ ws_sidx,
                                                    float* __restrict__ out) {
    __shared__ uint64_t keys[8192];                   // 64 KB
    const int r = blockIdx.x, t = threadIdx.x;
#pragma unroll
    for (int s = 0; s < 8; s++) {
        int i = t + (s << 10);
        uint32_t code = (uint32_t)ser[r * BN + ws_sidx[i]];   // < 2^30
        keys[i] = ((uint64_t)code << 13) | (uint32_t)i;       // unique keys => stable
    }
    __syncthreads();
    for (int k2 = 2; k2 <= 8192; k2 <<= 1) {
        for (int j = k2 >> 1; j > 0; j >>= 1) {
#pragma unroll 2
            for (int s = 0; s < 8; s++) {
                int i = t + (s << 10);
                int ixj = i ^ j;
                if (ixj > i) {
                    uint64_t a = keys[i], bq = keys[ixj];
                    bool up = ((i & k2) == 0);
                    if ((a > bq) == up) { keys[i] = bq; keys[ixj] = a; }
                }
            }
            __syncthreads();
        }
    }
    for (int s = 0; s < 8; s++) {
        int k = t + (s << 10);
        uint64_t key = keys[k];
        int i = (int)(key & 8191u);
        out[OFF_ORD + r*8192 + k] = (float)i;
        out[OFF_INV + r*8192 + i] = (float)k;
    }
}

// ---------------------------------------------------------------------------
extern "C" void kernel_launch(void* const* d_in, const int* in_sizes, int n_in,
                              void* d_out, int out_size, void* d_ws, size_t ws_size,
                              hipStream_t stream) {
    const float* coord = (const float*)d_in[0];
    const int*   ser   = (const int*)d_in[1];
    float* out = (float*)d_out;
    char* ws = (char*)d_ws;
    int* ws_sidx = (int*)(ws + WS_SIDX);
    int* ws_knn  = (int*)(ws + WS_KNN);

    hipLaunchKernelGGL(fps_kernel,  dim3(BB),   dim3(1024), 0, stream, coord, ws_sidx, out);
    hipLaunchKernelGGL(knn_kernel,  dim3(8192), dim3(64),   0, stream, coord, ws_sidx, ws_knn);
    hipLaunchKernelGGL(sxyz_kernel, dim3(96),   dim3(256),  0, stream, coord, ws_sidx, out);
    hipLaunchKernelGGL(sn_kernel,   dim3(2976), dim3(256),  0, stream, coord, ws_sidx, ws_knn, out);
    hipLaunchKernelGGL(sort_kernel, dim3(4),    dim3(1024), 0, stream, ser, ws_sidx, out);
}

// Round 4
// 2100.796 us; speedup vs baseline: 1.7655x; 1.0933x over previous
//
#include <hip/hip_runtime.h>
#include <hip/hip_bf16.h>
#include <stdint.h>

// Problem constants (fixed by setup_inputs)
#define BB 8
#define NN 16384
#define GG 1024
#define SS 32
#define BN (BB*NN)          // 131072

// Output offsets (elements, float32)
#define OFF_SIDX 0
#define OFF_SN   8192
#define OFF_SXYZ 770048     // 8192 + 8192*31*3
#define OFF_ORD  794624     // + 24576
#define OFF_INV  827392     // + 32768

// Workspace offsets (bytes)
#define WS_SIDX 0                    // int[8192]
#define WS_KNN  32768                // int[8192*32] = 1 MB

typedef float v2f __attribute__((ext_vector_type(2)));

static __device__ __forceinline__ v2f vmin2(v2f a, v2f b) {
    v2f r; r.x = fminf(a.x, b.x); r.y = fminf(a.y, b.y); return r;
}
static __device__ __forceinline__ v2f vmax2(v2f a, v2f b) {
    v2f r; r.x = fmaxf(a.x, b.x); r.y = fmaxf(a.y, b.y); return r;
}

static __device__ __forceinline__ uint64_t shfl_u64(uint64_t v, int src) {
    int lo = __shfl((int)(uint32_t)(v & 0xffffffffull), src, 64);
    int hi = __shfl((int)(uint32_t)(v >> 32), src, 64);
    return ((uint64_t)(uint32_t)hi << 32) | (uint32_t)lo;
}

// DPP-based unsigned max merge: o = dpp(v); return max(o, v).
// old = v and bound_ctrl = false => invalid/masked lanes keep v (idempotent).
template<int CTRL, int RM, int BM>
static __device__ __forceinline__ unsigned dpp_umax(unsigned v) {
    unsigned o = (unsigned)__builtin_amdgcn_update_dpp((int)v, (int)v, CTRL, RM, BM, false);
    return o > v ? o : v;
}

// ---------------------------------------------------------------------------
// 1) FPS: one block/batch, 1024 thr, 16 pts/thread as 8 float2 pairs.
//    Value-only DPP reductions (dist >= 0 so fp32 max == u32 max on bits);
//    exact first-argmax index via rare claimant atomicMin on p = t + e*1024.
// ---------------------------------------------------------------------------
__global__ __launch_bounds__(1024) void fps_kernel(const float* __restrict__ coord,
                                                   int* __restrict__ ws_sidx,
                                                   float* __restrict__ out) {
#pragma clang fp contract(off)
    const int b = blockIdx.x;
    const int t = threadIdx.x;
    const int base = b * NN;
    const int wave = t >> 6, lane = t & 63;

    // pair j covers point indices e=2j (x-slot) and e=2j+1 (y-slot), p = t + e*1024
    v2f px[8], py[8], pz[8], dist[8];
#pragma unroll
    for (int j = 0; j < 8; j++) {
        int pA = t + (j << 11);
        int pB = pA + 1024;
        px[j] = (v2f){coord[3*(base+pA)  ], coord[3*(base+pB)  ]};
        py[j] = (v2f){coord[3*(base+pA)+1], coord[3*(base+pB)+1]};
        pz[j] = (v2f){coord[3*(base+pA)+2], coord[3*(base+pB)+2]};
        dist[j] = (v2f){__builtin_inff(), __builtin_inff()};
    }

    __shared__ unsigned wv[16];       // per-wave max bits
    __shared__ unsigned win[2];       // packed winner p, double-buffered by parity

    if (t == 0) {
        ws_sidx[b*GG] = base;                 // selection 0 = index 0
        out[OFF_SIDX + b*GG] = (float)base;
        win[0] = 0xffffffffu; win[1] = 0xffffffffu;
    }
    // q0 = pts[0] (uniform scalar load)
    float qx = coord[3*base], qy = coord[3*base+1], qz = coord[3*base+2];
    __syncthreads();

    for (int g = 1; g < GG; g++) {
        const int s = g & 1;
        // ---- scan: dist = min(dist, |p-q|^2), bit-exact (no fma, left-assoc)
        v2f qvx = (v2f){qx,qx}, qvy = (v2f){qy,qy}, qvz = (v2f){qz,qz};
#pragma unroll
        for (int j = 0; j < 8; j++) {
            v2f dx = px[j] - qvx, dy = py[j] - qvy, dz = pz[j] - qvz;
            v2f d  = (dx*dx + dy*dy) + dz*dz;
            dist[j] = vmin2(dist[j], d);
        }
        // ---- per-thread max (value only), pk tree
        v2f m01 = vmax2(dist[0], dist[1]);
        v2f m23 = vmax2(dist[2], dist[3]);
        v2f m45 = vmax2(dist[4], dist[5]);
        v2f m67 = vmax2(dist[6], dist[7]);
        v2f m07 = vmax2(vmax2(m01, m23), vmax2(m45, m67));
        float bvf = fmaxf(m07.x, m07.y);
        unsigned lb = __float_as_uint(bvf);   // local max as orderable bits
        // ---- wave max via DPP (result lands in lane 63)
        unsigned r = lb;
        r = dpp_umax<0x111, 0xf, 0xf>(r);     // row_shr:1
        r = dpp_umax<0x112, 0xf, 0xf>(r);     // row_shr:2
        r = dpp_umax<0x114, 0xf, 0xf>(r);     // row_shr:4
        r = dpp_umax<0x118, 0xf, 0xf>(r);     // row_shr:8
        r = dpp_umax<0x142, 0xa, 0xf>(r);     // row_bcast:15 -> rows 1,3
        r = dpp_umax<0x143, 0xc, 0xf>(r);     // row_bcast:31 -> rows 2,3
        unsigned wmax = (unsigned)__builtin_amdgcn_readlane((int)r, 63);
        if (lane == 0) wv[wave] = wmax;
        __syncthreads();                      // B1: wv ready; win[s] reads of g-1 done
        if (t == 0) win[1 - s] = 0xffffffffu; // reset other slot for step g+1
        // ---- block max: 16 wave winners, 4-level DPP within rows of 16
        unsigned x = wv[lane & 15];
        x = dpp_umax<0x111, 0xf, 0xf>(x);
        x = dpp_umax<0x112, 0xf, 0xf>(x);
        x = dpp_umax<0x114, 0xf, 0xf>(x);
        x = dpp_umax<0x118, 0xf, 0xf>(x);
        unsigned bmax = (unsigned)__builtin_amdgcn_readlane((int)x, 15);
        // ---- claim: exact first-max index = min p, p = t + e*1024 (rare path)
        if (lb == bmax) {
            int e = 15;
#pragma unroll
            for (int jj = 15; jj >= 0; jj--) {
                float v = (jj & 1) ? dist[jj >> 1].y : dist[jj >> 1].x;
                if (__float_as_uint(v) == bmax) e = jj;
            }
            atomicMin(&win[s], (unsigned)(t + (e << 10)));
        }
        __syncthreads();                      // B2: winner resolved
        unsigned pw = win[s];
        int sp = __builtin_amdgcn_readfirstlane((int)pw);   // uniform winner
        if (t == 0) {
            ws_sidx[b*GG + g] = base + sp;
            out[OFF_SIDX + b*GG + g] = (float)(base + sp);
        }
        // uniform (scalar) reload of winner coords
        qx = coord[3*(base+sp)];
        qy = coord[3*(base+sp)+1];
        qz = coord[3*(base+sp)+2];
    }
}

// ---------------------------------------------------------------------------
// 2) kNN top-32: one wave per center, NO LDS (d2 recomputed on rescan ->
//    full occupancy: all 8192 waves resident). Bit-exact d2 both passes.
// ---------------------------------------------------------------------------
__global__ __launch_bounds__(64) void knn_kernel(const float* __restrict__ coord,
                                                 const int* __restrict__ ws_sidx,
                                                 int* __restrict__ ws_knn) {
#pragma clang fp contract(off)
    const int c = blockIdx.x;             // center 0..8191
    const int l = threadIdx.x;            // lane 0..63
    const int b = c >> 10;
    const int base = b * NN;
    const int sg = ws_sidx[c];            // global center index
    const float cx = coord[3*sg], cy = coord[3*sg+1], cz = coord[3*sg+2];
    const float cc = (cx*cx + cy*cy) + cz*cz;

    // phase 1: per-lane running min over stripe {l + 64*j}
    float mv = __builtin_inff(); int mp = 0;
#pragma unroll 4
    for (int j = 0; j < 256; j++) {
        int p = l + (j << 6);
        float x = coord[3*(base+p)], y = coord[3*(base+p)+1], z = coord[3*(base+p)+2];
        float pp  = (x*x + y*y) + z*z;
        float dot = (cx*x + cy*y) + cz*z;
        float d2  = (cc + pp) - 2.0f*dot;             // ref formula exactly
        if (d2 < mv) { mv = d2; mp = p; }             // j asc => p asc, strict <
    }

    uint64_t m0 = 0, m1 = 0, m2 = 0, m3 = 0;          // consumed bits, my stripe
    int res_p = 0;
    for (int k = 0; k < SS; k++) {
        // global argmin over per-lane minima (tie -> smaller index)
        float bv = mv; int bp = mp;
#pragma unroll
        for (int off = 32; off >= 1; off >>= 1) {
            float ov = __shfl_xor(bv, off, 64);
            int   op = __shfl_xor(bp, off, 64);
            if (ov < bv || (ov == bv && op < bp)) { bv = ov; bp = op; }
        }
        if (l == k) res_p = bp;                       // lane k keeps k-th neighbor
        const int w  = bp & 63;                       // winner lane / stripe
        const int e  = bp >> 6;                       // element within stripe
        if (l == w) {                                 // mark consumed
            uint64_t bit = 1ull << (e & 63);
            int word = e >> 6;
            if      (word == 0) m0 |= bit;
            else if (word == 1) m1 |= bit;
            else if (word == 2) m2 |= bit;
            else                m3 |= bit;
        }
        uint64_t w0 = shfl_u64(m0, w), w1 = shfl_u64(m1, w),
                 w2 = shfl_u64(m2, w), w3 = shfl_u64(m3, w);
        // rescan winner stripe (256 elems, 4/lane), d2 recomputed (bit-exact)
        float nv = __builtin_inff(); int np_ = 0;
#pragma unroll
        for (int m = 0; m < 4; m++) {
            int e2 = l + (m << 6);
            uint64_t mw = (m == 0) ? w0 : ((m == 1) ? w1 : ((m == 2) ? w2 : w3));
            int p2 = w + (e2 << 6);
            float x = coord[3*(base+p2)], y = coord[3*(base+p2)+1], z = coord[3*(base+p2)+2];
            float pp  = (x*x + y*y) + z*z;
            float dot = (cx*x + cy*y) + cz*z;
            float d2  = (cc + pp) - 2.0f*dot;
            bool cons = (mw >> l) & 1ull;
            if (!cons && d2 < nv) { nv = d2; np_ = p2; } // m asc => p2 asc
        }
#pragma unroll
        for (int off = 32; off >= 1; off >>= 1) {
            float ov = __shfl_xor(nv, off, 64);
            int   op = __shfl_xor(np_, off, 64);
            if (ov < nv || (ov == nv && op < np_)) { nv = ov; np_ = op; }
        }
        if (l == w) { mv = nv; mp = np_; }            // winner lane's new stripe-min
    }
    if (l < SS) ws_knn[c * SS + l] = res_p;           // local point index
}

// ---------------------------------------------------------------------------
// 3) s_xyz gather
// ---------------------------------------------------------------------------
__global__ void sxyz_kernel(const float* __restrict__ coord,
                            const int* __restrict__ ws_sidx,
                            float* __restrict__ out) {
    int t = blockIdx.x * blockDim.x + threadIdx.x;
    if (t < 8192*3) {
        int i = t / 3, cmp = t - 3*i;
        out[OFF_SXYZ + t] = coord[3*ws_sidx[i] + cmp];
    }
}

// ---------------------------------------------------------------------------
// 4) s_n = coord[knn[1..31]] - center
// ---------------------------------------------------------------------------
__global__ void sn_kernel(const float* __restrict__ coord,
                          const int* __restrict__ ws_sidx,
                          const int* __restrict__ ws_knn,
                          float* __restrict__ out) {
#pragma clang fp contract(off)
    int t = blockIdx.x * blockDim.x + threadIdx.x;
    if (t < 8192*31*3) {
        int cmp = t % 3; int rem = t / 3;
        int j = rem % 31; int i = rem / 31;
        int b = i >> 10;
        int nb = ws_knn[i*SS + j + 1];                // skip neighbor 0 (self)
        int gidx = b*NN + nb;
        float v = coord[3*gidx + cmp] - coord[3*ws_sidx[i] + cmp];
        out[OFF_SN + t] = v;
    }
}

// ---------------------------------------------------------------------------
// 5) stable argsort per code row: bitonic sort of (code<<13 | idx) in LDS
// ---------------------------------------------------------------------------
__global__ __launch_bounds__(1024) void sort_kernel(const int* __restrict__ ser,
                                                    const int* __restrict__ ws_sidx,
                                                    float* __restrict__ out) {
    __shared__ uint64_t keys[8192];                   // 64 KB
    const int r = blockIdx.x, t = threadIdx.x;
#pragma unroll
    for (int s = 0; s < 8; s++) {
        int i = t + (s << 10);
        uint32_t code = (uint32_t)ser[r * BN + ws_sidx[i]];   // < 2^30
        keys[i] = ((uint64_t)code << 13) | (uint32_t)i;       // unique keys => stable
    }
    __syncthreads();
    for (int k2 = 2; k2 <= 8192; k2 <<= 1) {
        for (int j = k2 >> 1; j > 0; j >>= 1) {
#pragma unroll 2
            for (int s = 0; s < 8; s++) {
                int i = t + (s << 10);
                int ixj = i ^ j;
                if (ixj > i) {
                    uint64_t a = keys[i], bq = keys[ixj];
                    bool up = ((i & k2) == 0);
                    if ((a > bq) == up) { keys[i] = bq; keys[ixj] = a; }
                }
            }
            __syncthreads();
        }
    }
    for (int s = 0; s < 8; s++) {
        int k = t + (s << 10);
        uint64_t key = keys[k];
        int i = (int)(key & 8191u);
        out[OFF_ORD + r*8192 + k] = (float)i;
        out[OFF_INV + r*8192 + i] = (float)k;
    }
}

// ---------------------------------------------------------------------------
extern "C" void kernel_launch(void* const* d_in, const int* in_sizes, int n_in,
                              void* d_out, int out_size, void* d_ws, size_t ws_size,
                              hipStream_t stream) {
    const float* coord = (const float*)d_in[0];
    const int*   ser   = (const int*)d_in[1];
    float* out = (float*)d_out;
    char* ws = (char*)d_ws;
    int* ws_sidx = (int*)(ws + WS_SIDX);
    int* ws_knn  = (int*)(ws + WS_KNN);

    hipLaunchKernelGGL(fps_kernel,  dim3(BB),   dim3(1024), 0, stream, coord, ws_sidx, out);
    hipLaunchKernelGGL(knn_kernel,  dim3(8192), dim3(64),   0, stream, coord, ws_sidx, ws_knn);
    hipLaunchKernelGGL(sxyz_kernel, dim3(96),   dim3(256),  0, stream, coord, ws_sidx, out);
    hipLaunchKernelGGL(sn_kernel,   dim3(2976), dim3(256),  0, stream, coord, ws_sidx, ws_knn, out);
    hipLaunchKernelGGL(sort_kernel, dim3(4),    dim3(1024), 0, stream, ser, ws_sidx, out);
}